// Round 4
// baseline (1228.358 us; speedup 1.0000x reference)
//
#include <hip/hip_runtime.h>

#define ALPHA   0.15f
#define RA      (1e-4f * 0.15f)                  // RHO*ALPHA
#define THRESH  ((1.0f + 0.01f) * 1e-4f * 0.15f) // (1+eps)*RHO*ALPHA
#define NITER   20
#define NS      8
#define WELL    32        // ELL width (deg ~ Poisson(15)+1; P(deg>32) ~ 1e-5)
#define OMAX    4096      // COO overflow capacity
#define NMIR    64        // flag mirrors to spread atomicOr contention

// ---------------------------------------------------------------------------
// init: zero ELL slab (int4), zero flag mirrors (+ initial bits), cursor=0,
// pd=(0,d0), dpk0; oCnt=0.
// ---------------------------------------------------------------------------
__global__ void init_kernel(const float* __restrict__ deg, const int* __restrict__ seeds,
                            float2* __restrict__ pd, float* __restrict__ dpk,
                            int* __restrict__ cursor, int2* __restrict__ cwPad,
                            int* __restrict__ flagM, int* __restrict__ oCnt, int N) {
    int idx = blockIdx.x * blockDim.x + threadIdx.x;
    int q = N * 16;                      // N*WELL int2 records == N*16 int4
    if (idx < q) ((int4*)cwPad)[idx] = make_int4(0, 0, 0, 0);
    if (idx < (NITER + 1) * NMIR) {
        int v = 0;
        if (idx == 0) {                  // initial flags live in mirror 0 of iter 0
            for (int s = 0; s < NS; ++s) {
                float m = ALPHA / fmaxf(deg[seeds[s]], 1e-12f);
                if (m > THRESH) v |= (1 << s);
            }
        }
        flagM[idx] = v;
    }
    if (idx == 0) *oCnt = 0;
    if (idx < N) {
        cursor[idx] = 0;
        float dv[NS];
#pragma unroll
        for (int s = 0; s < NS; ++s) dv[s] = 0.f;
#pragma unroll
        for (int s = 0; s < NS; ++s) {
            if (seeds[s] == idx) dv[s] = -ALPHA / fmaxf(deg[idx], 1e-12f);
        }
#pragma unroll
        for (int s = 0; s < NS; ++s) {
            pd[idx * NS + s] = make_float2(0.f, dv[s]);
            bool S = (0.f - dv[s]) >= RA;
            dpk[idx * NS + s] = S ? -(dv[s] + RA) : 0.f;
        }
    }
}

// ---------------------------------------------------------------------------
// scatter COO -> ELL(32)/overflow; record {col*NS, bits(w)}, w=v/(v*deg[c]+1e-12)
// ---------------------------------------------------------------------------
__global__ void scatter_kernel(const int* __restrict__ row, const int* __restrict__ col,
                               const float* __restrict__ val, const float* __restrict__ deg,
                               int* __restrict__ cursor, int2* __restrict__ cwPad,
                               int* __restrict__ oR, int2* __restrict__ oCW,
                               int* __restrict__ oCnt, int E) {
    int e = blockIdx.x * blockDim.x + threadIdx.x;
    if (e >= E) return;
    int r = row[e];
    int posn = atomicAdd(&cursor[r], 1);
    int c = col[e];
    float v = val[e];
    float w = v / (v * deg[c] + 1e-12f);
    int2 rec = make_int2(c * NS, __float_as_int(w));
    if (posn < WELL) {
        cwPad[(size_t)r * WELL + posn] = rec;
    } else {
        int i = atomicAdd(oCnt, 1);
        if (i < OMAX) { oR[i] = r; oCW[i] = rec; }
    }
}

// ---------------------------------------------------------------------------
// one iteration: wave per row. lanes = 8 edge-groups x 8 seeds.
// ELL fixed-trip unrolled loop (4x 64B coalesced cw loads + predicated 32B
// gathers, all issued up front -> 4-deep MLP, no dependent offs load).
// Fused node update; convergence flags via 64-mirror bitmask + atomicOr.
// ---------------------------------------------------------------------------
__global__ __launch_bounds__(256, 8) void update_kernel(
        const int2* __restrict__ cwPad, const float* __restrict__ deg,
        const int* __restrict__ oR, const int2* __restrict__ oCW,
        const int* __restrict__ oCnt,
        const int* __restrict__ flagIn, int* __restrict__ flagOut,
        const float* __restrict__ din, float* __restrict__ dout,
        float2* __restrict__ pd, float* __restrict__ outp, int last, int N) {
    int wid = (blockIdx.x * blockDim.x + threadIdx.x) >> 6;
    if (wid >= N) return;
    int lane = threadIdx.x & 63;
    int s = lane & 7;            // seed
    int g = lane >> 3;           // edge-slot group 0..7
    int r = wid;

    // gather iteration-k flags: OR over 64 mirrors via shuffles
    int fm = flagIn[lane];
#pragma unroll
    for (int o = 1; o < 64; o <<= 1) fm |= __shfl_xor(fm, o);

    if (fm == 0) {               // globally converged: p frozen
        if (last && lane < NS) outp[lane * N + r] = pd[r * NS + lane].x;
        return;
    }

    float acc = 0.f;
    const int2* rp = cwPad + (size_t)r * WELL;
#pragma unroll
    for (int j = 0; j < WELL / 8; ++j) {
        int2 cv = rp[j * 8 + g];             // 64B coalesced per j across the 8 groups
        float w = __int_as_float(cv.y);
        if (w != 0.f) acc = fmaf(w, din[cv.x + s], acc);   // pads (w==0) skip the gather
    }
    float dg = deg[r];
    if (dg > (float)WELL) {                  // rare overflow rows: scan COO list
        int oc = min(*oCnt, OMAX);
        for (int i = g; i < oc; i += 8) {
            if (oR[i] == r) {
                int2 cv = oCW[i];
                acc = fmaf(__int_as_float(cv.y), din[cv.x + s], acc);
            }
        }
    }
    acc += __shfl_xor(acc, 8);
    acc += __shfl_xor(acc, 16);
    acc += __shfl_xor(acc, 32);

    bool fire = false;
    if (lane < NS) {                         // lane == seed index here
        float2 pdv = pd[r * NS + lane];
        float pv = pdv.x, dv = pdv.y;
        float di = 1.0f / fmaxf(dg, 1e-12f);
        float half = 0.5f * (1.0f - ALPHA) * di;
        bool S = (pv - dv) >= RA;
        float dpkv = S ? -(dv + RA) : 0.f;
        float d_S  = (1.0f - di) * dv - RA * di - half * dpkv - half * acc;
        float d_nb = dv - half * acc;
        bool a = (fm >> lane) & 1;
        float d2 = a ? (S ? d_S : d_nb) : dv;
        float p2 = a ? (S ? pv + dpkv : pv) : pv;
        if (last) {
            outp[lane * N + r] = p2;
        } else {
            pd[r * NS + lane] = make_float2(p2, d2);
            dout[r * NS + lane] = ((p2 - d2) >= RA) ? -(d2 + RA) : 0.f;
            fire = a && (fabsf(d2) > THRESH);
        }
    }
    if (!last) {
        unsigned long long b = __ballot(fire);
        if (lane == 0) {
            int mask = (int)(b & 0xFFull);
            if (mask) {
                int h = wid & (NMIR - 1);
                int cur = __hip_atomic_load(&flagOut[h], __ATOMIC_RELAXED,
                                            __HIP_MEMORY_SCOPE_AGENT);
                if ((cur & mask) != mask) atomicOr(&flagOut[h], mask);
            }
        }
    }
}

extern "C" void kernel_launch(void* const* d_in, const int* in_sizes, int n_in,
                              void* d_out, int out_size, void* d_ws, size_t ws_size,
                              hipStream_t stream) {
    const int*   adj_row = (const int*)  d_in[0];
    const int*   adj_col = (const int*)  d_in[1];
    const float* adj_val = (const float*)d_in[2];
    const float* deg     = (const float*)d_in[3];
    const int*   seeds   = (const int*)  d_in[4];
    const int E = in_sizes[0];
    const int N = in_sizes[3];
    float* out = (float*)d_out;

    // workspace carve-up (256B aligned). dpkA aliases d_out (3.2MB saved):
    // ping-pong makes din=dpkB at k=19 (odd), so writing out over dpkA is safe.
    char* base = (char*)d_ws;
    size_t off = 0;
    auto carve = [&](size_t bytes) -> void* {
        off = (off + 255) & ~(size_t)255;
        void* ptr = base + off;
        off += bytes;
        return ptr;
    };
    float2* pd     = (float2*)carve((size_t)N * NS * 8);
    float*  dpkB   = (float*) carve((size_t)N * NS * 4);
    int2*   cwPad  = (int2*)  carve((size_t)N * WELL * 8);
    int*    cursor = (int*)   carve((size_t)N * 4);
    int*    oR     = (int*)   carve((size_t)OMAX * 4);
    int2*   oCW    = (int2*)  carve((size_t)OMAX * 8);
    int*    oCnt   = (int*)   carve(256);
    int*    flagM  = (int*)   carve((size_t)(NITER + 1) * NMIR * 4);
    float*  dpkA   = out;     // aliased

    int ib = (N * 16 + 255) / 256;   // covers slab-zero, N, flag mirrors
    init_kernel<<<ib, 256, 0, stream>>>(deg, seeds, pd, dpkA, cursor, cwPad,
                                        flagM, oCnt, N);
    int eb = (E + 255) / 256;
    scatter_kernel<<<eb, 256, 0, stream>>>(adj_row, adj_col, adj_val, deg,
                                           cursor, cwPad, oR, oCW, oCnt, E);

    float* din   = dpkA;
    float* dout_ = dpkB;
    int ub = (N + 3) / 4;            // 4 waves (rows) per 256-thread block
    for (int k = 0; k < NITER; ++k) {
        int last = (k == NITER - 1) ? 1 : 0;
        update_kernel<<<ub, 256, 0, stream>>>(cwPad, deg, oR, oCW, oCnt,
                                              flagM + k * NMIR, flagM + (k + 1) * NMIR,
                                              din, dout_, pd, out, last, N);
        float* t = din; din = dout_; dout_ = t;
    }
}

// Round 6
// 810.941 us; speedup vs baseline: 1.5147x; 1.5147x over previous
//
#include <hip/hip_runtime.h>

#define ALPHA   0.15f
#define RA      (1e-4f * 0.15f)                  // RHO*ALPHA
#define THRESH  ((1.0f + 0.01f) * 1e-4f * 0.15f) // (1+eps)*RHO*ALPHA
#define NITER   20
#define NS      8
#define NMIR    64       // flag mirrors to spread atomicOr contention
#define CH      16       // contiguous rows per wave (8 pairs via half-waves)

// ---------------------------------------------------------------------------
// init: pd=(0,d0); dpw0 = dpk0/(deg+1e-12); cursor=0; flag mirrors (+bits).
// ---------------------------------------------------------------------------
__global__ void init_kernel(const float* __restrict__ deg, const int* __restrict__ seeds,
                            float2* __restrict__ pd, float* __restrict__ dpw,
                            int* __restrict__ cursor, int* __restrict__ flagM, int N) {
    int idx = blockIdx.x * blockDim.x + threadIdx.x;
    if (idx < (NITER + 1) * NMIR) {
        int v = 0;
        if (idx == 0) {
            for (int s = 0; s < NS; ++s) {
                float m = ALPHA / fmaxf(deg[seeds[s]], 1e-12f);
                if (m > THRESH) v |= (1 << s);
            }
        }
        flagM[idx] = v;
    }
    if (idx >= N) return;
    cursor[idx] = 0;
    float dv[NS];
#pragma unroll
    for (int s = 0; s < NS; ++s) dv[s] = 0.f;
#pragma unroll
    for (int s = 0; s < NS; ++s) {
        if (seeds[s] == idx) dv[s] = -ALPHA / fmaxf(deg[idx], 1e-12f);
    }
    float den = deg[idx] + 1e-12f;
#pragma unroll
    for (int s = 0; s < NS; ++s) {
        pd[idx * NS + s] = make_float2(0.f, dv[s]);
        bool S = (0.f - dv[s]) >= RA;
        dpw[idx * NS + s] = S ? (-(dv[s] + RA) / den) : 0.f;
    }
}

// ---------------------------------------------------------------------------
// parallel exclusive scan of deg -> offs[0..N], three tiny kernels
// ---------------------------------------------------------------------------
__global__ void block_sum_kernel(const float* __restrict__ deg, int* __restrict__ blockSums, int N) {
    int i = blockIdx.x * 256 + threadIdx.x;
    int v = (i < N) ? (int)deg[i] : 0;
#pragma unroll
    for (int o = 1; o < 64; o <<= 1) v += __shfl_xor(v, o);
    __shared__ int ws[4];
    if ((threadIdx.x & 63) == 0) ws[threadIdx.x >> 6] = v;
    __syncthreads();
    if (threadIdx.x == 0) blockSums[blockIdx.x] = ws[0] + ws[1] + ws[2] + ws[3];
}

__global__ void scan_sums_kernel(const int* __restrict__ blockSums, int* __restrict__ blockOffs, int nB) {
    __shared__ int buf[1024];
    int t = threadIdx.x;
    int v = (t < nB) ? blockSums[t] : 0;
    buf[t] = v;
    __syncthreads();
    for (int o = 1; o < 1024; o <<= 1) {
        int u = (t >= o) ? buf[t - o] : 0;
        __syncthreads();
        buf[t] += u;
        __syncthreads();
    }
    if (t < nB) blockOffs[t] = buf[t] - v;  // exclusive
}

__global__ void write_offs_kernel(const float* __restrict__ deg, const int* __restrict__ blockOffs,
                                  int* __restrict__ offs, int N, int E) {
    int t = threadIdx.x;
    int i = blockIdx.x * 256 + t;
    int v = (i < N) ? (int)deg[i] : 0;
    __shared__ int buf[256];
    buf[t] = v;
    __syncthreads();
    for (int o = 1; o < 256; o <<= 1) {
        int u = (t >= o) ? buf[t - o] : 0;
        __syncthreads();
        buf[t] += u;
        __syncthreads();
    }
    int excl = buf[t] - v;
    if (i < N) offs[i] = blockOffs[blockIdx.x] + excl;
    if (i == 0) offs[N] = E;   // sum(deg) == E by construction (deg = bincount(row))
}

// ---------------------------------------------------------------------------
// scatter COO -> CSR; record = col*NS (4B). No weight: gather table pre-scaled.
// ---------------------------------------------------------------------------
__global__ void scatter_kernel(const int* __restrict__ row, const int* __restrict__ col,
                               const int* __restrict__ offs, int* __restrict__ cursor,
                               int* __restrict__ cols, int E) {
    int e = blockIdx.x * blockDim.x + threadIdx.x;
    if (e >= E) return;
    int r = row[e];
    int pos = offs[r] + atomicAdd(&cursor[r], 1);
    cols[pos] = col[e] * NS;
}

// ---------------------------------------------------------------------------
// one iteration. Wave owns CH=16 contiguous rows, processed as 8 pairs:
// half-wave h handles row base+2j+h with 4 edge-groups x 8 seeds.
// acc = sum_e dpw_in[cols[e]+s]; fused node update writes pd, dpw_out
// (pre-scaled by 1/(deg[r]+1e-12)), convergence bits via mirror atomicOr.
// ---------------------------------------------------------------------------
__global__ __launch_bounds__(256, 8) void update_kernel(
        const int* __restrict__ offs, const int* __restrict__ cols,
        const float* __restrict__ deg,
        const int* __restrict__ flagIn, int* __restrict__ flagOut,
        const float* __restrict__ din, float* __restrict__ dout,
        float2* __restrict__ pd, float* __restrict__ outp, int last, int N) {
    int wid = (blockIdx.x * blockDim.x + threadIdx.x) >> 6;
    int lane = threadIdx.x & 63;
    int base = wid * CH;
    if (base >= N) return;

    // iteration-k flags: OR over 64 mirrors via shuffles
    int fm = flagIn[lane];
#pragma unroll
    for (int o = 1; o < 64; o <<= 1) fm |= __shfl_xor(fm, o);

    int h  = lane >> 5;         // half: row parity
    int l5 = lane & 31;
    int s  = l5 & 7;            // seed
    int g  = l5 >> 3;           // edge group 0..3

    if (fm == 0) {              // globally converged: p frozen
        if (last) {
#pragma unroll
            for (int j = 0; j < CH / 2; ++j) {
                int r = base + 2 * j + h;
                if (r < N && l5 < NS) outp[s * N + r] = pd[r * NS + s].x;
            }
        }
        return;
    }

    int offv = 0;
    if (lane <= CH) offv = offs[min(base + lane, N)];

    int wmask = 0;
    for (int j = 0; j < CH / 2; ++j) {
        int r = base + 2 * j + h;
        int e0 = __shfl(offv, 2 * j + h);
        int e1 = __shfl(offv, 2 * j + h + 1);
        float acc = 0.f;
        if (r < N) {
            for (int e = e0 + g; e < e1; e += 4) {
                acc += din[cols[e] + s];
            }
        }
        acc += __shfl_xor(acc, 8);
        acc += __shfl_xor(acc, 16);

        bool fire = false;
        if (l5 < NS && r < N) {             // s == l5 here
            float2 pdv = pd[r * NS + s];
            float pv = pdv.x, dv = pdv.y;
            float dg = deg[r];
            float di = 1.0f / fmaxf(dg, 1e-12f);
            float half = 0.5f * (1.0f - ALPHA) * di;
            bool S = (pv - dv) >= RA;
            float dpkv = S ? -(dv + RA) : 0.f;
            float d_S  = (1.0f - di) * dv - RA * di - half * dpkv - half * acc;
            float d_nb = dv - half * acc;
            bool a = (fm >> s) & 1;
            float d2 = a ? (S ? d_S : d_nb) : dv;
            float p2 = a ? (S ? pv + dpkv : pv) : pv;
            if (last) {
                outp[s * N + r] = p2;
            } else {
                pd[r * NS + s] = make_float2(p2, d2);
                float den = dg + 1e-12f;
                bool S2 = (p2 - d2) >= RA;
                dout[r * NS + s] = S2 ? (-(d2 + RA) / den) : 0.f;
                fire = a && (fabsf(d2) > THRESH);
            }
        }
        unsigned long long b = __ballot(fire);
        wmask |= (int)((b & 0xFFull) | ((b >> 32) & 0xFFull));
    }

    if (!last && wmask && lane == 0) {
        int hsh = wid & (NMIR - 1);
        int cur = __hip_atomic_load(&flagOut[hsh], __ATOMIC_RELAXED,
                                    __HIP_MEMORY_SCOPE_AGENT);
        if ((cur & wmask) != wmask) atomicOr(&flagOut[hsh], wmask);
    }
}

extern "C" void kernel_launch(void* const* d_in, const int* in_sizes, int n_in,
                              void* d_out, int out_size, void* d_ws, size_t ws_size,
                              hipStream_t stream) {
    const int*   adj_row = (const int*)  d_in[0];
    const int*   adj_col = (const int*)  d_in[1];
    const float* deg     = (const float*)d_in[3];
    const int*   seeds   = (const int*)  d_in[4];
    const int E = in_sizes[0];
    const int N = in_sizes[3];
    float* out = (float*)d_out;

    // workspace carve-up (256B aligned). dpwA aliases d_out:
    // with 19 swaps, din at k=19 is dpwB, so writing out over dpwA is safe;
    // out is fully rewritten (both normal and early-exit paths) at k=19.
    char* base = (char*)d_ws;
    size_t off = 0;
    auto carve = [&](size_t bytes) -> void* {
        off = (off + 255) & ~(size_t)255;
        void* ptr = base + off;
        off += bytes;
        return ptr;
    };
    float2* pd     = (float2*)carve((size_t)N * NS * 8);
    float*  dpwB   = (float*) carve((size_t)N * NS * 4);
    int*    cols   = (int*)   carve((size_t)E * 4);
    int*    offs   = (int*)   carve((size_t)(N + 1) * 4);
    int*    cursor = (int*)   carve((size_t)N * 4);
    int*    bsums  = (int*)   carve((size_t)1024 * 4);
    int*    boffs  = (int*)   carve((size_t)1024 * 4);
    int*    flagM  = (int*)   carve((size_t)(NITER + 1) * NMIR * 4);
    float*  dpwA   = out;     // aliased

    int nb = (N + 255) / 256;      // 391 blocks
    init_kernel<<<nb, 256, 0, stream>>>(deg, seeds, pd, dpwA, cursor, flagM, N);
    block_sum_kernel<<<nb, 256, 0, stream>>>(deg, bsums, N);
    scan_sums_kernel<<<1, 1024, 0, stream>>>(bsums, boffs, nb);
    write_offs_kernel<<<nb, 256, 0, stream>>>(deg, boffs, offs, N, E);
    int eb = (E + 255) / 256;
    scatter_kernel<<<eb, 256, 0, stream>>>(adj_row, adj_col, offs, cursor, cols, E);

    float* din   = dpwA;
    float* dout_ = dpwB;
    int waves = (N + CH - 1) / CH;
    int ub = (waves + 3) / 4;      // 4 waves per 256-thread block
    for (int k = 0; k < NITER; ++k) {
        int last = (k == NITER - 1) ? 1 : 0;
        update_kernel<<<ub, 256, 0, stream>>>(offs, cols, deg,
                                              flagM + k * NMIR, flagM + (k + 1) * NMIR,
                                              din, dout_, pd, out, last, N);
        float* t = din; din = dout_; dout_ = t;
    }
}

// Round 7
// 687.306 us; speedup vs baseline: 1.7872x; 1.1799x over previous
//
#include <hip/hip_runtime.h>

#define ALPHA   0.15f
#define RA      (1e-4f * 0.15f)                  // RHO*ALPHA
#define THRESH  ((1.0f + 0.01f) * 1e-4f * 0.15f) // (1+eps)*RHO*ALPHA
#define NITER   20
#define NS      8
#define NMIR    64       // flag mirrors to spread atomicOr contention
#define CH      16       // contiguous rows per wave (8 pairs via half-waves)
#define SPAN    512      // LDS staging capacity per wave (mean 256, +16 sigma safe)
#define NBIN    8        // scatter row-bins (== XCDs)
#define ECHUNK  2048     // edges per scatter chunk

// ---------------------------------------------------------------------------
// init: pd=(0,d0); dpw0 = dpk0/(deg+1e-12); cursor=0; flag mirrors (+bits).
// ---------------------------------------------------------------------------
__global__ void init_kernel(const float* __restrict__ deg, const int* __restrict__ seeds,
                            float2* __restrict__ pd, float* __restrict__ dpw,
                            int* __restrict__ cursor, int* __restrict__ flagM, int N) {
    int idx = blockIdx.x * blockDim.x + threadIdx.x;
    if (idx < (NITER + 1) * NMIR) {
        int v = 0;
        if (idx == 0) {
            for (int s = 0; s < NS; ++s) {
                float m = ALPHA / fmaxf(deg[seeds[s]], 1e-12f);
                if (m > THRESH) v |= (1 << s);
            }
        }
        flagM[idx] = v;
    }
    if (idx >= N) return;
    cursor[idx] = 0;
    float dv[NS];
#pragma unroll
    for (int s = 0; s < NS; ++s) dv[s] = 0.f;
#pragma unroll
    for (int s = 0; s < NS; ++s) {
        if (seeds[s] == idx) dv[s] = -ALPHA / fmaxf(deg[idx], 1e-12f);
    }
    float den = deg[idx] + 1e-12f;
#pragma unroll
    for (int s = 0; s < NS; ++s) {
        pd[idx * NS + s] = make_float2(0.f, dv[s]);
        bool S = (0.f - dv[s]) >= RA;
        dpw[idx * NS + s] = S ? (-(dv[s] + RA) / den) : 0.f;
    }
}

// ---------------------------------------------------------------------------
// parallel exclusive scan of deg -> offs[0..N], three tiny kernels
// ---------------------------------------------------------------------------
__global__ void block_sum_kernel(const float* __restrict__ deg, int* __restrict__ blockSums, int N) {
    int i = blockIdx.x * 256 + threadIdx.x;
    int v = (i < N) ? (int)deg[i] : 0;
#pragma unroll
    for (int o = 1; o < 64; o <<= 1) v += __shfl_xor(v, o);
    __shared__ int ws[4];
    if ((threadIdx.x & 63) == 0) ws[threadIdx.x >> 6] = v;
    __syncthreads();
    if (threadIdx.x == 0) blockSums[blockIdx.x] = ws[0] + ws[1] + ws[2] + ws[3];
}

__global__ void scan_sums_kernel(const int* __restrict__ blockSums, int* __restrict__ blockOffs, int nB) {
    __shared__ int buf[1024];
    int t = threadIdx.x;
    int v = (t < nB) ? blockSums[t] : 0;
    buf[t] = v;
    __syncthreads();
    for (int o = 1; o < 1024; o <<= 1) {
        int u = (t >= o) ? buf[t - o] : 0;
        __syncthreads();
        buf[t] += u;
        __syncthreads();
    }
    if (t < nB) blockOffs[t] = buf[t] - v;  // exclusive
}

__global__ void write_offs_kernel(const float* __restrict__ deg, const int* __restrict__ blockOffs,
                                  int* __restrict__ offs, int N, int E) {
    int t = threadIdx.x;
    int i = blockIdx.x * 256 + t;
    int v = (i < N) ? (int)deg[i] : 0;
    __shared__ int buf[256];
    buf[t] = v;
    __syncthreads();
    for (int o = 1; o < 256; o <<= 1) {
        int u = (t >= o) ? buf[t - o] : 0;
        __syncthreads();
        buf[t] += u;
        __syncthreads();
    }
    int excl = buf[t] - v;
    if (i < N) offs[i] = blockOffs[blockIdx.x] + excl;
    if (i == 0) offs[N] = E;   // sum(deg) == E by construction (deg = bincount(row))
}

// ---------------------------------------------------------------------------
// scatter COO -> CSR, XCD-binned: block (chunk,bin=bid%8) scans its chunk and
// writes only rows in its bin -> cols/cursor writes stay XCD-L2-local.
// record = col*NS (4B), weight folded into the gathered table.
// ---------------------------------------------------------------------------
__global__ void scatter_kernel(const int* __restrict__ row, const int* __restrict__ col,
                               const int* __restrict__ offs, int* __restrict__ cursor,
                               int* __restrict__ cols, int E, int N) {
    int bin = blockIdx.x & (NBIN - 1);
    int chunk = blockIdx.x >> 3;
    int binW = (N + NBIN - 1) / NBIN;
    int binLo = bin * binW;
    int binHi = min(N, binLo + binW);
    int e = chunk * ECHUNK + threadIdx.x;
#pragma unroll
    for (int i = 0; i < ECHUNK / 256; ++i, e += 256) {
        if (e < E) {
            int r = row[e];
            if (r >= binLo && r < binHi) {
                int pos = offs[r] + atomicAdd(&cursor[r], 1);
                cols[pos] = col[e] * NS;
            }
        }
    }
}

// ---------------------------------------------------------------------------
// one iteration. Wave owns CH=16 contiguous rows (8 pairs via half-waves).
// Phase A: stage the wave's contiguous CSR slice into LDS (coalesced).
// Phase B: fixed-trip 8x8 unrolled gather -> independent din loads (deep MLP);
// rare deg>32 rows take a runtime fallback from global. Fused node update,
// convergence bits via mirror atomicOr.
// ---------------------------------------------------------------------------
__global__ __launch_bounds__(256, 8) void update_kernel(
        const int* __restrict__ offs, const int* __restrict__ cols,
        const float* __restrict__ deg,
        const int* __restrict__ flagIn, int* __restrict__ flagOut,
        const float* __restrict__ din, float* __restrict__ dout,
        float2* __restrict__ pd, float* __restrict__ outp, int last, int N) {
    __shared__ int sCols[4][SPAN];
    int wid = (blockIdx.x * blockDim.x + threadIdx.x) >> 6;
    int lane = threadIdx.x & 63;
    int w = (threadIdx.x >> 6) & 3;
    int base = wid * CH;
    if (base >= N) return;

    // iteration-k flags: OR over 64 mirrors via shuffles
    int fm = flagIn[lane];
#pragma unroll
    for (int o = 1; o < 64; o <<= 1) fm |= __shfl_xor(fm, o);

    int h  = lane >> 5;         // half: row parity
    int l5 = lane & 31;
    int s  = l5 & 7;            // seed
    int g  = l5 >> 3;           // edge group 0..3

    if (fm == 0) {              // globally converged: p frozen
        if (last) {
#pragma unroll
            for (int j = 0; j < CH / 2; ++j) {
                int r = base + 2 * j + h;
                if (r < N && l5 < NS) outp[s * N + r] = pd[r * NS + s].x;
            }
        }
        return;
    }

    int offv = 0;
    if (lane <= CH) offv = offs[min(base + lane, N)];
    int off0 = __shfl(offv, 0);
    int span = __shfl(offv, CH) - off0;

    // Phase A: stage CSR slice (wave-private LDS region; no barrier needed)
    for (int i = lane; i < span; i += 64) sCols[w][i] = cols[off0 + i];

    int wmask = 0;
#pragma unroll
    for (int j = 0; j < CH / 2; ++j) {
        int r = base + 2 * j + h;
        int e0 = __shfl(offv, 2 * j + h);
        int e1 = __shfl(offv, 2 * j + h + 1);
        int rel = e0 - off0;
        int nd = e1 - e0;
        float acc = 0.f;
#pragma unroll
        for (int m = 0; m < 8; ++m) {
            int slot = g + 4 * m;
            int idx = min(rel + slot, SPAN - 1);
            int c = sCols[w][idx];
            if (slot < nd) acc += din[c + s];   // exec-masked gather
        }
        if (nd > 32) {                          // rare overflow: global fallback
            for (int e = e0 + 32 + g; e < e1; e += 4) acc += din[cols[e] + s];
        }
        acc += __shfl_xor(acc, 8);
        acc += __shfl_xor(acc, 16);

        bool fire = false;
        if (l5 < NS && r < N) {                 // s == l5 here
            float2 pdv = pd[r * NS + s];
            float pv = pdv.x, dv = pdv.y;
            float dg = deg[r];
            float di = 1.0f / fmaxf(dg, 1e-12f);
            float half = 0.5f * (1.0f - ALPHA) * di;
            bool S = (pv - dv) >= RA;
            float dpkv = S ? -(dv + RA) : 0.f;
            float d_S  = (1.0f - di) * dv - RA * di - half * dpkv - half * acc;
            float d_nb = dv - half * acc;
            bool a = (fm >> s) & 1;
            float d2 = a ? (S ? d_S : d_nb) : dv;
            float p2 = a ? (S ? pv + dpkv : pv) : pv;
            if (last) {
                outp[s * N + r] = p2;
            } else {
                pd[r * NS + s] = make_float2(p2, d2);
                float den = dg + 1e-12f;
                bool S2 = (p2 - d2) >= RA;
                dout[r * NS + s] = S2 ? (-(d2 + RA) / den) : 0.f;
                fire = a && (fabsf(d2) > THRESH);
            }
        }
        unsigned long long b = __ballot(fire);
        wmask |= (int)((b & 0xFFull) | ((b >> 32) & 0xFFull));
    }

    if (!last && wmask && lane == 0) {
        int hsh = wid & (NMIR - 1);
        int cur = __hip_atomic_load(&flagOut[hsh], __ATOMIC_RELAXED,
                                    __HIP_MEMORY_SCOPE_AGENT);
        if ((cur & wmask) != wmask) atomicOr(&flagOut[hsh], wmask);
    }
}

extern "C" void kernel_launch(void* const* d_in, const int* in_sizes, int n_in,
                              void* d_out, int out_size, void* d_ws, size_t ws_size,
                              hipStream_t stream) {
    const int*   adj_row = (const int*)  d_in[0];
    const int*   adj_col = (const int*)  d_in[1];
    const float* deg     = (const float*)d_in[3];
    const int*   seeds   = (const int*)  d_in[4];
    const int E = in_sizes[0];
    const int N = in_sizes[3];
    float* out = (float*)d_out;

    // workspace carve-up (256B aligned). dpwA aliases d_out:
    // with 19 swaps, din at k=19 is dpwB, so writing out over dpwA is safe;
    // out is fully rewritten (both normal and early-exit paths) at k=19.
    char* base = (char*)d_ws;
    size_t off = 0;
    auto carve = [&](size_t bytes) -> void* {
        off = (off + 255) & ~(size_t)255;
        void* ptr = base + off;
        off += bytes;
        return ptr;
    };
    float2* pd     = (float2*)carve((size_t)N * NS * 8);
    float*  dpwB   = (float*) carve((size_t)N * NS * 4);
    int*    cols   = (int*)   carve((size_t)(E + SPAN) * 4);   // +pad for staging overrun
    int*    offs   = (int*)   carve((size_t)(N + 1) * 4);
    int*    cursor = (int*)   carve((size_t)N * 4);
    int*    bsums  = (int*)   carve((size_t)1024 * 4);
    int*    boffs  = (int*)   carve((size_t)1024 * 4);
    int*    flagM  = (int*)   carve((size_t)(NITER + 1) * NMIR * 4);
    float*  dpwA   = out;     // aliased

    int nb = (N + 255) / 256;      // 391 blocks
    init_kernel<<<nb, 256, 0, stream>>>(deg, seeds, pd, dpwA, cursor, flagM, N);
    block_sum_kernel<<<nb, 256, 0, stream>>>(deg, bsums, N);
    scan_sums_kernel<<<1, 1024, 0, stream>>>(bsums, boffs, nb);
    write_offs_kernel<<<nb, 256, 0, stream>>>(deg, boffs, offs, N, E);
    int chunks = (E + ECHUNK - 1) / ECHUNK;
    scatter_kernel<<<chunks * NBIN, 256, 0, stream>>>(adj_row, adj_col, offs, cursor,
                                                      cols, E, N);

    float* din   = dpwA;
    float* dout_ = dpwB;
    int waves = (N + CH - 1) / CH;
    int ub = (waves + 3) / 4;      // 4 waves per 256-thread block
    for (int k = 0; k < NITER; ++k) {
        int last = (k == NITER - 1) ? 1 : 0;
        update_kernel<<<ub, 256, 0, stream>>>(offs, cols, deg,
                                              flagM + k * NMIR, flagM + (k + 1) * NMIR,
                                              din, dout_, pd, out, last, N);
        float* t = din; din = dout_; dout_ = t;
    }
}

// Round 8
// 581.188 us; speedup vs baseline: 2.1135x; 1.1826x over previous
//
#include <hip/hip_runtime.h>

#define ALPHA   0.15f
#define RA      (1e-4f * 0.15f)                  // RHO*ALPHA
#define THRESH  ((1.0f + 0.01f) * 1e-4f * 0.15f) // (1+eps)*RHO*ALPHA
#define NITER   20
#define NS      8
#define NMIR    64       // flag mirrors to spread atomicOr contention
#define CHV     8        // rows per wave
#define BLK     512      // threads per block (8 waves -> 64 rows per block)
#define SPAN    256      // LDS cols capacity per wave (mean 128, +11 sigma)
#define NBIN    8        // scatter row-bins (== XCDs)
#define ECHUNK  2048     // edges per scatter chunk
#define NWMAX   3136     // mask words capacity (N/32 = 3125)

// ---------------------------------------------------------------------------
// init: pd=(0,d0); dpw0 = dpk0/(deg+1e-12); cursor=0; flag mirrors; maskA.
// ---------------------------------------------------------------------------
__global__ void init_kernel(const float* __restrict__ deg, const int* __restrict__ seeds,
                            float2* __restrict__ pd, float* __restrict__ dpw,
                            int* __restrict__ cursor, int* __restrict__ flagM,
                            unsigned* __restrict__ maskA, int N) {
    int idx = blockIdx.x * blockDim.x + threadIdx.x;
    int NW = (N + 31) >> 5;
    if (idx < (NITER + 1) * NMIR) {
        int v = 0;
        if (idx == 0) {
            for (int s = 0; s < NS; ++s) {
                float m = ALPHA / fmaxf(deg[seeds[s]], 1e-12f);
                if (m > THRESH) v |= (1 << s);
            }
        }
        flagM[idx] = v;
    }
    if (idx < NW) {                 // frontier mask for iter 0: seed bits
        unsigned v = 0;
        for (int s = 0; s < NS; ++s) {
            int sd = seeds[s];
            bool S0 = (ALPHA / fmaxf(deg[sd], 1e-12f)) >= RA;
            if (S0 && (sd >> 5) == idx) v |= (1u << (sd & 31));
        }
        maskA[idx] = v;
    }
    if (idx >= N) return;
    cursor[idx] = 0;
    float dv[NS];
#pragma unroll
    for (int s = 0; s < NS; ++s) dv[s] = 0.f;
#pragma unroll
    for (int s = 0; s < NS; ++s) {
        if (seeds[s] == idx) dv[s] = -ALPHA / fmaxf(deg[idx], 1e-12f);
    }
    float den = deg[idx] + 1e-12f;
#pragma unroll
    for (int s = 0; s < NS; ++s) {
        pd[idx * NS + s] = make_float2(0.f, dv[s]);
        bool S = (0.f - dv[s]) >= RA;
        dpw[idx * NS + s] = S ? (-(dv[s] + RA) / den) : 0.f;
    }
}

// ---------------------------------------------------------------------------
// parallel exclusive scan of deg -> offs[0..N], three tiny kernels
// ---------------------------------------------------------------------------
__global__ void block_sum_kernel(const float* __restrict__ deg, int* __restrict__ blockSums, int N) {
    int i = blockIdx.x * 256 + threadIdx.x;
    int v = (i < N) ? (int)deg[i] : 0;
#pragma unroll
    for (int o = 1; o < 64; o <<= 1) v += __shfl_xor(v, o);
    __shared__ int ws[4];
    if ((threadIdx.x & 63) == 0) ws[threadIdx.x >> 6] = v;
    __syncthreads();
    if (threadIdx.x == 0) blockSums[blockIdx.x] = ws[0] + ws[1] + ws[2] + ws[3];
}

__global__ void scan_sums_kernel(const int* __restrict__ blockSums, int* __restrict__ blockOffs, int nB) {
    __shared__ int buf[1024];
    int t = threadIdx.x;
    int v = (t < nB) ? blockSums[t] : 0;
    buf[t] = v;
    __syncthreads();
    for (int o = 1; o < 1024; o <<= 1) {
        int u = (t >= o) ? buf[t - o] : 0;
        __syncthreads();
        buf[t] += u;
        __syncthreads();
    }
    if (t < nB) blockOffs[t] = buf[t] - v;  // exclusive
}

__global__ void write_offs_kernel(const float* __restrict__ deg, const int* __restrict__ blockOffs,
                                  int* __restrict__ offs, int N, int E) {
    int t = threadIdx.x;
    int i = blockIdx.x * 256 + t;
    int v = (i < N) ? (int)deg[i] : 0;
    __shared__ int buf[256];
    buf[t] = v;
    __syncthreads();
    for (int o = 1; o < 256; o <<= 1) {
        int u = (t >= o) ? buf[t - o] : 0;
        __syncthreads();
        buf[t] += u;
        __syncthreads();
    }
    int excl = buf[t] - v;
    if (i < N) offs[i] = blockOffs[blockIdx.x] + excl;
    if (i == 0) offs[N] = E;   // sum(deg) == E by construction (deg = bincount(row))
}

// ---------------------------------------------------------------------------
// scatter COO -> CSR, XCD-binned; record = plain col (4B).
// ---------------------------------------------------------------------------
__global__ void scatter_kernel(const int* __restrict__ row, const int* __restrict__ col,
                               const int* __restrict__ offs, int* __restrict__ cursor,
                               int* __restrict__ cols, int E, int N) {
    int bin = blockIdx.x & (NBIN - 1);
    int chunk = blockIdx.x >> 3;
    int binW = (N + NBIN - 1) / NBIN;
    int binLo = bin * binW;
    int binHi = min(N, binLo + binW);
    int e = chunk * ECHUNK + threadIdx.x;
#pragma unroll
    for (int i = 0; i < ECHUNK / 256; ++i, e += 256) {
        if (e < E) {
            int r = row[e];
            if (r >= binLo && r < binHi) {
                int pos = offs[r] + atomicAdd(&cursor[r], 1);
                cols[pos] = col[e];
            }
        }
    }
}

// ---------------------------------------------------------------------------
// one iteration. Block = 8 waves x CHV=8 rows. Phase 0: stage 12.5KB frontier
// bitmask + wave CSR slices into LDS. Gather loop tests the bit per edge and
// issues the din gather only for nonzero columns (exact: skips add-zero).
// Next-iteration mask assembled per block in LDS, plain-stored (2 words).
// ---------------------------------------------------------------------------
__global__ __launch_bounds__(BLK, 8) void update_kernel(
        const int* __restrict__ offs, const int* __restrict__ cols,
        const float* __restrict__ deg,
        const int* __restrict__ flagIn, int* __restrict__ flagOut,
        const unsigned* __restrict__ maskIn, unsigned* __restrict__ maskOut,
        const float* __restrict__ din, float* __restrict__ dout,
        float2* __restrict__ pd, float* __restrict__ outp, int last, int N) {
    __shared__ unsigned smask[NWMAX];
    __shared__ int sCols[BLK / 64][SPAN];
    __shared__ unsigned sRow[BLK / 64];
    int tid = threadIdx.x;
    int w = tid >> 6;
    int lane = tid & 63;
    int wid = blockIdx.x * (BLK / 64) + w;
    int base = wid * CHV;
    int NW = (N + 31) >> 5;
    bool rowsOk = (base < N);

    // iteration-k flags: OR over 64 mirrors via shuffles (grid-uniform value)
    int fm = flagIn[lane];
#pragma unroll
    for (int o = 1; o < 64; o <<= 1) fm |= __shfl_xor(fm, o);
    bool active = (fm != 0);

    if (active) {
        for (int i = tid; i < NW; i += BLK) smask[i] = maskIn[i];
    }

    int h  = lane >> 5;         // half: row parity
    int l5 = lane & 31;
    int s  = l5 & 7;            // seed
    int g  = l5 >> 3;           // edge group 0..3

    int offv = 0;
    if (lane <= CHV) offv = offs[min(base + lane, N)];
    int off0 = __shfl(offv, 0);
    int span = __shfl(offv, CHV) - off0;

    if (active && rowsOk) {
        int lim = min(span, SPAN);
        for (int i = lane; i < lim; i += 64) sCols[w][i] = cols[off0 + i];
    }
    __syncthreads();

    int wmask = 0;
    unsigned rbits = 0;
    if (active && rowsOk) {
#pragma unroll
        for (int j = 0; j < CHV / 2; ++j) {
            int r = base + 2 * j + h;
            int e0 = __shfl(offv, 2 * j + h);
            int e1 = __shfl(offv, 2 * j + h + 1);
            int rel = e0 - off0;
            int nd = e1 - e0;
            float acc = 0.f;
#pragma unroll
            for (int m = 0; m < 8; ++m) {
                int slot = g + 4 * m;
                int q = rel + slot;
                int cc = (q < SPAN) ? sCols[w][min(q, SPAN - 1)] : cols[off0 + q];
                if (slot < nd && ((smask[cc >> 5] >> (cc & 31)) & 1u)) {
                    acc += din[cc * NS + s];
                }
            }
            if (nd > 32) {                          // rare overflow: global fallback
                for (int e = e0 + 32 + g; e < e1; e += 4) {
                    int cc = cols[e];
                    if ((smask[cc >> 5] >> (cc & 31)) & 1u) acc += din[cc * NS + s];
                }
            }
            acc += __shfl_xor(acc, 8);
            acc += __shfl_xor(acc, 16);

            bool fire = false;
            bool nzflag = false;
            if (l5 < NS) {                          // s == l5 here
                float2 pdv = pd[r * NS + s];
                float pv = pdv.x, dv = pdv.y;
                float dg = deg[r];
                float di = 1.0f / fmaxf(dg, 1e-12f);
                float half = 0.5f * (1.0f - ALPHA) * di;
                bool S = (pv - dv) >= RA;
                float dpkv = S ? -(dv + RA) : 0.f;
                float d_S  = (1.0f - di) * dv - RA * di - half * dpkv - half * acc;
                float d_nb = dv - half * acc;
                bool a = (fm >> s) & 1;
                float d2 = a ? (S ? d_S : d_nb) : dv;
                float p2 = a ? (S ? pv + dpkv : pv) : pv;
                if (last) {
                    outp[s * N + r] = p2;
                } else {
                    pd[r * NS + s] = make_float2(p2, d2);
                    float den = dg + 1e-12f;
                    bool S2 = (p2 - d2) >= RA;
                    float dpw2 = S2 ? (-(d2 + RA) / den) : 0.f;
                    dout[r * NS + s] = dpw2;
                    fire = a && (fabsf(d2) > THRESH);
                    nzflag = (dpw2 != 0.f);
                }
            }
            unsigned long long b = __ballot(fire);
            wmask |= (int)((b & 0xFFull) | ((b >> 32) & 0xFFull));
            unsigned long long nb = __ballot(nzflag);
            if (nb & 0xFFull)         rbits |= 1u << (2 * j);
            if ((nb >> 32) & 0xFFull) rbits |= 1u << (2 * j + 1);
        }
    } else if (!active && rowsOk && last) {
        // globally converged: p frozen, emit
#pragma unroll
        for (int j = 0; j < CHV / 2; ++j) {
            int r = base + 2 * j + h;
            if (l5 < NS) outp[s * N + r] = pd[r * NS + s].x;
        }
    }

    if (!last) {
        if (lane == 0) sRow[w] = (active && rowsOk) ? rbits : 0u;
        __syncthreads();
        if (tid < 2) {   // assemble this block's 2 mask words (64 rows)
            unsigned wv = 0;
#pragma unroll
            for (int q = 0; q < 4; ++q) wv |= sRow[tid * 4 + q] << (8 * q);
            int word = blockIdx.x * 2 + tid;
            if (word < NW) maskOut[word] = wv;
        }
        if (wmask && lane == 0) {
            int hsh = wid & (NMIR - 1);
            int cur = __hip_atomic_load(&flagOut[hsh], __ATOMIC_RELAXED,
                                        __HIP_MEMORY_SCOPE_AGENT);
            if ((cur & wmask) != wmask) atomicOr(&flagOut[hsh], wmask);
        }
    }
}

extern "C" void kernel_launch(void* const* d_in, const int* in_sizes, int n_in,
                              void* d_out, int out_size, void* d_ws, size_t ws_size,
                              hipStream_t stream) {
    const int*   adj_row = (const int*)  d_in[0];
    const int*   adj_col = (const int*)  d_in[1];
    const float* deg     = (const float*)d_in[3];
    const int*   seeds   = (const int*)  d_in[4];
    const int E = in_sizes[0];
    const int N = in_sizes[3];
    float* out = (float*)d_out;
    int NW = (N + 31) >> 5;

    // workspace carve-up (256B aligned). dpwA aliases d_out:
    // din at k=19 is dpwB (19 swaps), so writing out over dpwA is safe.
    char* base = (char*)d_ws;
    size_t off = 0;
    auto carve = [&](size_t bytes) -> void* {
        off = (off + 255) & ~(size_t)255;
        void* ptr = base + off;
        off += bytes;
        return ptr;
    };
    float2*   pd     = (float2*)  carve((size_t)N * NS * 8);
    float*    dpwB   = (float*)   carve((size_t)N * NS * 4);
    int*      cols   = (int*)     carve((size_t)(E + SPAN) * 4);   // +pad for clamp reads
    int*      offs   = (int*)     carve((size_t)(N + 1) * 4);
    int*      cursor = (int*)     carve((size_t)N * 4);
    int*      bsums  = (int*)     carve((size_t)1024 * 4);
    int*      boffs  = (int*)     carve((size_t)1024 * 4);
    int*      flagM  = (int*)     carve((size_t)(NITER + 1) * NMIR * 4);
    unsigned* maskA  = (unsigned*)carve((size_t)NWMAX * 4);
    unsigned* maskB  = (unsigned*)carve((size_t)NWMAX * 4);
    float*    dpwA   = out;     // aliased

    int nb = (N + 255) / 256;      // 391 blocks
    init_kernel<<<nb, 256, 0, stream>>>(deg, seeds, pd, dpwA, cursor, flagM, maskA, N);
    block_sum_kernel<<<nb, 256, 0, stream>>>(deg, bsums, N);
    scan_sums_kernel<<<1, 1024, 0, stream>>>(bsums, boffs, nb);
    write_offs_kernel<<<nb, 256, 0, stream>>>(deg, boffs, offs, N, E);
    int chunks = (E + ECHUNK - 1) / ECHUNK;
    scatter_kernel<<<chunks * NBIN, 256, 0, stream>>>(adj_row, adj_col, offs, cursor,
                                                      cols, E, N);

    float*    din   = dpwA;
    float*    dout_ = dpwB;
    unsigned* mIn   = maskA;
    unsigned* mOut  = maskB;
    int rowsPerBlk = (BLK / 64) * CHV;                 // 64
    int ub = (N + rowsPerBlk - 1) / rowsPerBlk;        // 1563 blocks
    for (int k = 0; k < NITER; ++k) {
        int last = (k == NITER - 1) ? 1 : 0;
        update_kernel<<<ub, BLK, 0, stream>>>(offs, cols, deg,
                                              flagM + k * NMIR, flagM + (k + 1) * NMIR,
                                              mIn, mOut, din, dout_, pd, out, last, N);
        float* t = din; din = dout_; dout_ = t;
        unsigned* mt = mIn; mIn = mOut; mOut = mt;
    }
}

// Round 9
// 537.401 us; speedup vs baseline: 2.2857x; 1.0815x over previous
//
#include <hip/hip_runtime.h>

#define ALPHA   0.15f
#define RA      (1e-4f * 0.15f)                  // RHO*ALPHA
#define THRESH  ((1.0f + 0.01f) * 1e-4f * 0.15f) // (1+eps)*RHO*ALPHA
#define NITER   20
#define NS      8
#define NMIR    64       // flag mirrors to spread atomicOr contention
#define CHV     8        // rows per wave
#define BLK     256      // 4 waves/block -> 32 rows/block -> 3125 blocks (low tail)
#define W4      (BLK / 64)
#define SPAN    256      // LDS cols capacity per wave (mean 128, +11 sigma)
#define NBIN    8        // scatter row-bins (== XCDs)
#define ECHUNK  2048     // edges per scatter chunk
#define NWMAX   3136     // mask words capacity (N/32 = 3125)

// ---------------------------------------------------------------------------
// init: pd=(0,d0); dpw0 = dpk0/(deg+1e-12); cursor=0; flag mirrors; maskA.
// ---------------------------------------------------------------------------
__global__ void init_kernel(const float* __restrict__ deg, const int* __restrict__ seeds,
                            float2* __restrict__ pd, float* __restrict__ dpw,
                            int* __restrict__ cursor, int* __restrict__ flagM,
                            unsigned* __restrict__ maskA, int N) {
    int idx = blockIdx.x * blockDim.x + threadIdx.x;
    int NW = (N + 31) >> 5;
    if (idx < (NITER + 1) * NMIR) {
        int v = 0;
        if (idx == 0) {
            for (int s = 0; s < NS; ++s) {
                float m = ALPHA / fmaxf(deg[seeds[s]], 1e-12f);
                if (m > THRESH) v |= (1 << s);
            }
        }
        flagM[idx] = v;
    }
    if (idx < NW) {                 // frontier mask for iter 0: seed bits
        unsigned v = 0;
        for (int s = 0; s < NS; ++s) {
            int sd = seeds[s];
            bool S0 = (ALPHA / fmaxf(deg[sd], 1e-12f)) >= RA;
            if (S0 && (sd >> 5) == idx) v |= (1u << (sd & 31));
        }
        maskA[idx] = v;
    }
    if (idx >= N) return;
    cursor[idx] = 0;
    float dv[NS];
#pragma unroll
    for (int s = 0; s < NS; ++s) dv[s] = 0.f;
#pragma unroll
    for (int s = 0; s < NS; ++s) {
        if (seeds[s] == idx) dv[s] = -ALPHA / fmaxf(deg[idx], 1e-12f);
    }
    float den = deg[idx] + 1e-12f;
#pragma unroll
    for (int s = 0; s < NS; ++s) {
        pd[idx * NS + s] = make_float2(0.f, dv[s]);
        bool S = (0.f - dv[s]) >= RA;
        dpw[idx * NS + s] = S ? (-(dv[s] + RA) / den) : 0.f;
    }
}

// ---------------------------------------------------------------------------
// parallel exclusive scan of deg -> offs[0..N], three tiny kernels
// ---------------------------------------------------------------------------
__global__ void block_sum_kernel(const float* __restrict__ deg, int* __restrict__ blockSums, int N) {
    int i = blockIdx.x * 256 + threadIdx.x;
    int v = (i < N) ? (int)deg[i] : 0;
#pragma unroll
    for (int o = 1; o < 64; o <<= 1) v += __shfl_xor(v, o);
    __shared__ int ws[4];
    if ((threadIdx.x & 63) == 0) ws[threadIdx.x >> 6] = v;
    __syncthreads();
    if (threadIdx.x == 0) blockSums[blockIdx.x] = ws[0] + ws[1] + ws[2] + ws[3];
}

__global__ void scan_sums_kernel(const int* __restrict__ blockSums, int* __restrict__ blockOffs, int nB) {
    __shared__ int buf[1024];
    int t = threadIdx.x;
    int v = (t < nB) ? blockSums[t] : 0;
    buf[t] = v;
    __syncthreads();
    for (int o = 1; o < 1024; o <<= 1) {
        int u = (t >= o) ? buf[t - o] : 0;
        __syncthreads();
        buf[t] += u;
        __syncthreads();
    }
    if (t < nB) blockOffs[t] = buf[t] - v;  // exclusive
}

__global__ void write_offs_kernel(const float* __restrict__ deg, const int* __restrict__ blockOffs,
                                  int* __restrict__ offs, int N, int E) {
    int t = threadIdx.x;
    int i = blockIdx.x * 256 + t;
    int v = (i < N) ? (int)deg[i] : 0;
    __shared__ int buf[256];
    buf[t] = v;
    __syncthreads();
    for (int o = 1; o < 256; o <<= 1) {
        int u = (t >= o) ? buf[t - o] : 0;
        __syncthreads();
        buf[t] += u;
        __syncthreads();
    }
    int excl = buf[t] - v;
    if (i < N) offs[i] = blockOffs[blockIdx.x] + excl;
    if (i == 0) offs[N] = E;   // sum(deg) == E by construction (deg = bincount(row))
}

// ---------------------------------------------------------------------------
// scatter COO -> CSR, XCD-binned; record = plain col (4B), nontemporal store.
// ---------------------------------------------------------------------------
__global__ void scatter_kernel(const int* __restrict__ row, const int* __restrict__ col,
                               const int* __restrict__ offs, int* __restrict__ cursor,
                               int* __restrict__ cols, int E, int N) {
    int bin = blockIdx.x & (NBIN - 1);
    int chunk = blockIdx.x >> 3;
    int binW = (N + NBIN - 1) / NBIN;
    int binLo = bin * binW;
    int binHi = min(N, binLo + binW);
    int e = chunk * ECHUNK + threadIdx.x;
#pragma unroll
    for (int i = 0; i < ECHUNK / 256; ++i, e += 256) {
        if (e < E) {
            int r = row[e];
            if (r >= binLo && r < binHi) {
                int pos = offs[r] + atomicAdd(&cursor[r], 1);
                __builtin_nontemporal_store(col[e], &cols[pos]);
            }
        }
    }
}

// ---------------------------------------------------------------------------
// one iteration. Block = 4 waves x CHV=8 rows = 32 rows. Stage 12.5KB frontier
// bitmask + wave CSR slices into LDS. Gather phase fully hoisted: 32 predicated
// din gathers + 4 pd/deg loads issued before any reduce -> deep MLP. Then 4
// reduce+update phases. Next-iter mask word (1/block) assembled via LDS.
// ---------------------------------------------------------------------------
__global__ __launch_bounds__(BLK, 6) void update_kernel(
        const int* __restrict__ offs, const int* __restrict__ cols,
        const float* __restrict__ deg,
        const int* __restrict__ flagIn, int* __restrict__ flagOut,
        const unsigned* __restrict__ maskIn, unsigned* __restrict__ maskOut,
        const float* __restrict__ din, float* __restrict__ dout,
        float2* __restrict__ pd, float* __restrict__ outp, int last, int N) {
    __shared__ unsigned smask[NWMAX];
    __shared__ int sCols[W4][SPAN];
    __shared__ unsigned sRow[W4];
    int tid = threadIdx.x;
    int w = tid >> 6;
    int lane = tid & 63;
    int wid = blockIdx.x * W4 + w;
    int base = wid * CHV;
    int NW = (N + 31) >> 5;
    bool rowsOk = (base < N);

    // iteration-k flags: OR over 64 mirrors via shuffles (grid-uniform value)
    int fm = flagIn[lane];
#pragma unroll
    for (int o = 1; o < 64; o <<= 1) fm |= __shfl_xor(fm, o);
    bool active = (fm != 0);

    if (active) {
        for (int i = tid; i < NW; i += BLK) smask[i] = maskIn[i];
    }

    int h  = lane >> 5;         // half: row parity
    int l5 = lane & 31;
    int s  = l5 & 7;            // seed
    int g  = l5 >> 3;           // edge group 0..3

    int offv = 0;
    if (lane <= CHV) offv = offs[min(base + lane, N)];
    int off0 = __shfl(offv, 0);
    int span = __shfl(offv, CHV) - off0;
    bool fits = (span <= SPAN);

    if (active && rowsOk) {
        int lim = min(span, SPAN);
        for (int i = lane; i < lim; i += 64) sCols[w][i] = cols[off0 + i];
    }
    __syncthreads();

    int wmask = 0;
    unsigned rbits = 0;
    if (active && rowsOk) {
        float  acc[4];
        int    rel[4], nd[4];
        float2 pdv[4];
        float  dgv[4];
#pragma unroll
        for (int j = 0; j < 4; ++j) {
            int e0 = __shfl(offv, 2 * j + h);
            int e1 = __shfl(offv, 2 * j + h + 1);
            rel[j] = e0 - off0; nd[j] = e1 - e0; acc[j] = 0.f;
            int r = base + 2 * j + h;
            dgv[j] = deg[r];
            if (l5 < NS) pdv[j] = pd[r * NS + s];   // hoisted, issues early
        }
        if (fits) {
#pragma unroll
            for (int j = 0; j < 4; ++j) {
#pragma unroll
                for (int m = 0; m < 8; ++m) {
                    int slot = g + 4 * m;
                    int q = (rel[j] + slot) & (SPAN - 1);
                    int cc = sCols[w][q];
                    if (slot < nd[j] && ((smask[cc >> 5] >> (cc & 31)) & 1u))
                        acc[j] += din[cc * NS + s];
                }
            }
#pragma unroll
            for (int j = 0; j < 4; ++j) {          // rare deg>32: rest from LDS
                if (nd[j] > 32) {
                    for (int slot = 32 + g; slot < nd[j]; slot += 4) {
                        int cc = sCols[w][rel[j] + slot];
                        if ((smask[cc >> 5] >> (cc & 31)) & 1u) acc[j] += din[cc * NS + s];
                    }
                }
            }
        } else {                                   // astronomically rare slice
            for (int j = 0; j < 4; ++j) {
                for (int slot = g; slot < nd[j]; slot += 4) {
                    int cc = cols[off0 + rel[j] + slot];
                    if ((smask[cc >> 5] >> (cc & 31)) & 1u) acc[j] += din[cc * NS + s];
                }
            }
        }
#pragma unroll
        for (int j = 0; j < 4; ++j) {
            float a2 = acc[j];
            a2 += __shfl_xor(a2, 8);
            a2 += __shfl_xor(a2, 16);
            int r = base + 2 * j + h;
            bool fire = false;
            bool nzflag = false;
            if (l5 < NS) {                          // s == l5 here
                float pv = pdv[j].x, dv = pdv[j].y;
                float dg = dgv[j];
                float di = 1.0f / fmaxf(dg, 1e-12f);
                float half = 0.5f * (1.0f - ALPHA) * di;
                bool S = (pv - dv) >= RA;
                float dpkv = S ? -(dv + RA) : 0.f;
                float d_S  = (1.0f - di) * dv - RA * di - half * dpkv - half * a2;
                float d_nb = dv - half * a2;
                bool a = (fm >> s) & 1;
                float d2 = a ? (S ? d_S : d_nb) : dv;
                float p2 = a ? (S ? pv + dpkv : pv) : pv;
                if (last) {
                    outp[s * N + r] = p2;
                } else {
                    pd[r * NS + s] = make_float2(p2, d2);
                    float den = dg + 1e-12f;
                    bool S2 = (p2 - d2) >= RA;
                    float dpw2 = S2 ? (-(d2 + RA) / den) : 0.f;
                    dout[r * NS + s] = dpw2;
                    fire = a && (fabsf(d2) > THRESH);
                    nzflag = (dpw2 != 0.f);
                }
            }
            unsigned long long b = __ballot(fire);
            wmask |= (int)((b & 0xFFull) | ((b >> 32) & 0xFFull));
            unsigned long long nb = __ballot(nzflag);
            if (nb & 0xFFull)         rbits |= 1u << (2 * j);
            if ((nb >> 32) & 0xFFull) rbits |= 1u << (2 * j + 1);
        }
    } else if (!active && rowsOk && last) {
        // globally converged: p frozen, emit
#pragma unroll
        for (int j = 0; j < 4; ++j) {
            int r = base + 2 * j + h;
            if (l5 < NS) outp[s * N + r] = pd[r * NS + s].x;
        }
    }

    if (!last) {
        if (lane == 0) sRow[w] = (active && rowsOk) ? rbits : 0u;
        __syncthreads();
        if (tid == 0) {   // assemble this block's mask word (32 rows)
            unsigned wv = sRow[0] | (sRow[1] << 8) | (sRow[2] << 16) | (sRow[3] << 24);
            if (blockIdx.x < NW) maskOut[blockIdx.x] = wv;
        }
        if (wmask && lane == 0) {
            int hsh = wid & (NMIR - 1);
            int cur = __hip_atomic_load(&flagOut[hsh], __ATOMIC_RELAXED,
                                        __HIP_MEMORY_SCOPE_AGENT);
            if ((cur & wmask) != wmask) atomicOr(&flagOut[hsh], wmask);
        }
    }
}

extern "C" void kernel_launch(void* const* d_in, const int* in_sizes, int n_in,
                              void* d_out, int out_size, void* d_ws, size_t ws_size,
                              hipStream_t stream) {
    const int*   adj_row = (const int*)  d_in[0];
    const int*   adj_col = (const int*)  d_in[1];
    const float* deg     = (const float*)d_in[3];
    const int*   seeds   = (const int*)  d_in[4];
    const int E = in_sizes[0];
    const int N = in_sizes[3];
    float* out = (float*)d_out;

    // workspace carve-up (256B aligned). dpwA aliases d_out:
    // din at k=19 is dpwB (19 swaps), so writing out over dpwA is safe.
    char* base = (char*)d_ws;
    size_t off = 0;
    auto carve = [&](size_t bytes) -> void* {
        off = (off + 255) & ~(size_t)255;
        void* ptr = base + off;
        off += bytes;
        return ptr;
    };
    float2*   pd     = (float2*)  carve((size_t)N * NS * 8);
    float*    dpwB   = (float*)   carve((size_t)N * NS * 4);
    int*      cols   = (int*)     carve((size_t)(E + SPAN) * 4);
    int*      offs   = (int*)     carve((size_t)(N + 1) * 4);
    int*      cursor = (int*)     carve((size_t)N * 4);
    int*      bsums  = (int*)     carve((size_t)1024 * 4);
    int*      boffs  = (int*)     carve((size_t)1024 * 4);
    int*      flagM  = (int*)     carve((size_t)(NITER + 1) * NMIR * 4);
    unsigned* maskA  = (unsigned*)carve((size_t)NWMAX * 4);
    unsigned* maskB  = (unsigned*)carve((size_t)NWMAX * 4);
    float*    dpwA   = out;     // aliased

    int nb = (N + 255) / 256;      // 391 blocks
    init_kernel<<<nb, 256, 0, stream>>>(deg, seeds, pd, dpwA, cursor, flagM, maskA, N);
    block_sum_kernel<<<nb, 256, 0, stream>>>(deg, bsums, N);
    scan_sums_kernel<<<1, 1024, 0, stream>>>(bsums, boffs, nb);
    write_offs_kernel<<<nb, 256, 0, stream>>>(deg, boffs, offs, N, E);
    int chunks = (E + ECHUNK - 1) / ECHUNK;
    scatter_kernel<<<chunks * NBIN, 256, 0, stream>>>(adj_row, adj_col, offs, cursor,
                                                      cols, E, N);

    float*    din   = dpwA;
    float*    dout_ = dpwB;
    unsigned* mIn   = maskA;
    unsigned* mOut  = maskB;
    int rowsPerBlk = W4 * CHV;                         // 32
    int ub = (N + rowsPerBlk - 1) / rowsPerBlk;        // 3125 blocks
    for (int k = 0; k < NITER; ++k) {
        int last = (k == NITER - 1) ? 1 : 0;
        update_kernel<<<ub, BLK, 0, stream>>>(offs, cols, deg,
                                              flagM + k * NMIR, flagM + (k + 1) * NMIR,
                                              mIn, mOut, din, dout_, pd, out, last, N);
        float* t = din; din = dout_; dout_ = t;
        unsigned* mt = mIn; mIn = mOut; mOut = mt;
    }
}

// Round 10
// 379.371 us; speedup vs baseline: 3.2379x; 1.4166x over previous
//
#include <hip/hip_runtime.h>

#define ALPHA   0.15f
#define RA      (1e-4f * 0.15f)                  // RHO*ALPHA
#define THRESH  ((1.0f + 0.01f) * 1e-4f * 0.15f) // (1+eps)*RHO*ALPHA
#define NITER   20
#define NS      8
#define NMIR    64       // flag mirrors to spread atomicOr contention
#define CHW     32       // rows per wave (2 lanes/row)
#define BLK     256      // 4 waves/block -> 128 rows/block -> 782 blocks
#define W4      (BLK / 64)
#define SPAN    768      // LDS cols capacity per wave (mean 512, +11 sigma)
#define NBIN    8        // scatter row-bins (== XCDs)
#define ECHUNK  2048     // edges per scatter chunk
#define NWMAX   3136     // mask words capacity (N/32 = 3125)

// ---------------------------------------------------------------------------
// init: pd=(0,d0); dpw0 = dpk0/(deg+1e-12); cursor=0; flag mirrors; maskA.
// ---------------------------------------------------------------------------
__global__ void init_kernel(const float* __restrict__ deg, const int* __restrict__ seeds,
                            float2* __restrict__ pd, float* __restrict__ dpw,
                            int* __restrict__ cursor, int* __restrict__ flagM,
                            unsigned* __restrict__ maskA, int N) {
    int idx = blockIdx.x * blockDim.x + threadIdx.x;
    int NW = (N + 31) >> 5;
    if (idx < (NITER + 1) * NMIR) {
        int v = 0;
        if (idx == 0) {
            for (int s = 0; s < NS; ++s) {
                float m = ALPHA / fmaxf(deg[seeds[s]], 1e-12f);
                if (m > THRESH) v |= (1 << s);
            }
        }
        flagM[idx] = v;
    }
    if (idx < NW) {                 // frontier mask for iter 0: seed bits
        unsigned v = 0;
        for (int s = 0; s < NS; ++s) {
            int sd = seeds[s];
            bool S0 = (ALPHA / fmaxf(deg[sd], 1e-12f)) >= RA;
            if (S0 && (sd >> 5) == idx) v |= (1u << (sd & 31));
        }
        maskA[idx] = v;
    }
    if (idx >= N) return;
    cursor[idx] = 0;
    float dv[NS];
#pragma unroll
    for (int s = 0; s < NS; ++s) dv[s] = 0.f;
#pragma unroll
    for (int s = 0; s < NS; ++s) {
        if (seeds[s] == idx) dv[s] = -ALPHA / fmaxf(deg[idx], 1e-12f);
    }
    float den = deg[idx] + 1e-12f;
#pragma unroll
    for (int s = 0; s < NS; ++s) {
        pd[idx * NS + s] = make_float2(0.f, dv[s]);
        bool S = (0.f - dv[s]) >= RA;
        dpw[idx * NS + s] = S ? (-(dv[s] + RA) / den) : 0.f;
    }
}

// ---------------------------------------------------------------------------
// parallel exclusive scan of deg -> offs[0..N], three tiny kernels
// ---------------------------------------------------------------------------
__global__ void block_sum_kernel(const float* __restrict__ deg, int* __restrict__ blockSums, int N) {
    int i = blockIdx.x * 256 + threadIdx.x;
    int v = (i < N) ? (int)deg[i] : 0;
#pragma unroll
    for (int o = 1; o < 64; o <<= 1) v += __shfl_xor(v, o);
    __shared__ int ws[4];
    if ((threadIdx.x & 63) == 0) ws[threadIdx.x >> 6] = v;
    __syncthreads();
    if (threadIdx.x == 0) blockSums[blockIdx.x] = ws[0] + ws[1] + ws[2] + ws[3];
}

__global__ void scan_sums_kernel(const int* __restrict__ blockSums, int* __restrict__ blockOffs, int nB) {
    __shared__ int buf[1024];
    int t = threadIdx.x;
    int v = (t < nB) ? blockSums[t] : 0;
    buf[t] = v;
    __syncthreads();
    for (int o = 1; o < 1024; o <<= 1) {
        int u = (t >= o) ? buf[t - o] : 0;
        __syncthreads();
        buf[t] += u;
        __syncthreads();
    }
    if (t < nB) blockOffs[t] = buf[t] - v;  // exclusive
}

__global__ void write_offs_kernel(const float* __restrict__ deg, const int* __restrict__ blockOffs,
                                  int* __restrict__ offs, int N, int E) {
    int t = threadIdx.x;
    int i = blockIdx.x * 256 + t;
    int v = (i < N) ? (int)deg[i] : 0;
    __shared__ int buf[256];
    buf[t] = v;
    __syncthreads();
    for (int o = 1; o < 256; o <<= 1) {
        int u = (t >= o) ? buf[t - o] : 0;
        __syncthreads();
        buf[t] += u;
        __syncthreads();
    }
    int excl = buf[t] - v;
    if (i < N) offs[i] = blockOffs[blockIdx.x] + excl;
    if (i == 0) offs[N] = E;   // sum(deg) == E by construction (deg = bincount(row))
}

// ---------------------------------------------------------------------------
// scatter COO -> CSR, XCD-binned; record = plain col (4B). (nt-store reverted)
// ---------------------------------------------------------------------------
__global__ void scatter_kernel(const int* __restrict__ row, const int* __restrict__ col,
                               const int* __restrict__ offs, int* __restrict__ cursor,
                               int* __restrict__ cols, int E, int N) {
    int bin = blockIdx.x & (NBIN - 1);
    int chunk = blockIdx.x >> 3;
    int binW = (N + NBIN - 1) / NBIN;
    int binLo = bin * binW;
    int binHi = min(N, binLo + binW);
    int e = chunk * ECHUNK + threadIdx.x;
#pragma unroll
    for (int i = 0; i < ECHUNK / 256; ++i, e += 256) {
        if (e < E) {
            int r = row[e];
            if (r >= binLo && r < binHi) {
                int pos = offs[r] + atomicAdd(&cursor[r], 1);
                cols[pos] = col[e];
            }
        }
    }
}

// ---------------------------------------------------------------------------
// one iteration. Wave = 32 rows x 2 seed-half lanes. Stage frontier bitmask
// (block) + wave CSR slice with mask folded in (-1 sentinel). Gather: each
// lane walks its row's slots sequentially, float4 (4 seeds) per edge; the two
// half-lanes of an edge cover one 32B din row. No cross-lane reduction. Fused
// scalar update (4 seeds/lane); pd store skipped when row unchanged; dout
// store skipped when row mask bit is 0 (never read). Wave == one mask word.
// ---------------------------------------------------------------------------
__global__ __launch_bounds__(BLK, 4) void update_kernel(
        const int* __restrict__ offs, const int* __restrict__ cols,
        const float* __restrict__ deg,
        const int* __restrict__ flagIn, int* __restrict__ flagOut,
        const unsigned* __restrict__ maskIn, unsigned* __restrict__ maskOut,
        const float* __restrict__ din, float* __restrict__ dout,
        float2* __restrict__ pd, float* __restrict__ outp, int last, int N) {
    __shared__ unsigned smask[NWMAX];
    __shared__ int sColsAll[W4 * SPAN];
    int tid = threadIdx.x;
    int w = tid >> 6;
    int lane = tid & 63;
    int wid = blockIdx.x * W4 + w;          // wave id == mask word index
    int base = wid * CHW;
    int NW = (N + 31) >> 5;
    int* sCols = sColsAll + w * SPAN;

    int r  = lane >> 1;                     // row-in-wave 0..31
    int sh = lane & 1;                      // seed-half (seeds 4sh..4sh+3)
    int row = base + r;
    bool rok = row < N;

    // iteration-k flags: OR over 64 mirrors via shuffles (grid-uniform value)
    int fm = flagIn[lane];
#pragma unroll
    for (int o = 1; o < 64; o <<= 1) fm |= __shfl_xor(fm, o);

    if (fm == 0) {                          // globally converged: p frozen
        if (last && rok) {
            const float4* pp = (const float4*)(pd + (size_t)row * NS + 4 * sh);
            float4 A = pp[0], B = pp[1];
            outp[(4 * sh + 0) * (size_t)N + row] = A.x;
            outp[(4 * sh + 1) * (size_t)N + row] = A.z;
            outp[(4 * sh + 2) * (size_t)N + row] = B.x;
            outp[(4 * sh + 3) * (size_t)N + row] = B.z;
        }
        return;
    }

    for (int i = tid; i < NW; i += BLK) smask[i] = maskIn[i];
    __syncthreads();

    int offv = 0;
    if (lane <= CHW) offv = offs[min(base + lane, N)];
    int off0 = __shfl(offv, 0);
    int span = __shfl(offv, CHW) - off0;
    int e0 = __shfl(offv, r);
    int e1 = __shfl(offv, r + 1);
    int rel = e0 - off0, ndg = e1 - e0;

    bool fits = (span <= SPAN);
    if (fits) {                             // stage cols with mask folded in
        for (int i = lane; i < span; i += 64) {
            int cc = cols[off0 + i];
            sCols[i] = ((smask[cc >> 5] >> (cc & 31)) & 1u) ? cc : -1;
        }
    }
    // no barrier needed: sCols region is wave-private

    int mx = ndg;
#pragma unroll
    for (int o = 1; o < 64; o <<= 1) mx = max(mx, __shfl_xor(mx, o));

    float a0 = 0.f, a1 = 0.f, a2 = 0.f, a3 = 0.f;
    const float4* din4 = (const float4*)din;
    if (fits) {
#pragma unroll 4
        for (int i = 0; i < mx; ++i) {
            int idx = (i < ndg) ? (rel + i) : 0;
            int cc = sCols[idx];
            if (i < ndg && cc >= 0) {
                float4 v = din4[(size_t)cc * 2 + sh];
                a0 += v.x; a1 += v.y; a2 += v.z; a3 += v.w;
            }
        }
    } else {                                // astronomically rare slice
        for (int i = 0; i < mx; ++i) {
            if (i < ndg) {
                int cc = cols[e0 + i];
                if ((smask[cc >> 5] >> (cc & 31)) & 1u) {
                    float4 v = din4[(size_t)cc * 2 + sh];
                    a0 += v.x; a1 += v.y; a2 += v.z; a3 += v.w;
                }
            }
        }
    }

    float dg = 1.0f;
    if (rok) dg = deg[row];
    float di = 1.0f / fmaxf(dg, 1e-12f);
    float hf = 0.5f * (1.0f - ALPHA) * di;
    float den = dg + 1e-12f;

    float4 pdA = make_float4(0.f, 0.f, 0.f, 0.f), pdB = pdA;
    if (rok) {
        const float4* pp = (const float4*)(pd + (size_t)row * NS + 4 * sh);
        pdA = pp[0]; pdB = pp[1];
    }
    float p0 = pdA.x, d0 = pdA.y, p1 = pdA.z, d1 = pdA.w;
    float p2v = pdB.x, d2v = pdB.y, p3 = pdB.z, d3 = pdB.w;
    float w0, w1, w2, w3;
    unsigned fireN = 0, nzN = 0;
    bool chg = false;

#define UPD(PK, DK, AK, K, WK) { \
        bool S = (PK - DK) >= RA; \
        float dpkv = S ? -(DK + RA) : 0.f; \
        float dS  = (1.0f - di) * DK - RA * di - hf * dpkv - hf * AK; \
        float dnb = DK - hf * AK; \
        bool aa = (fm >> (4 * sh + K)) & 1; \
        float nd2 = aa ? (S ? dS : dnb) : DK; \
        float np2 = aa ? (S ? PK + dpkv : PK) : PK; \
        bool S2 = (np2 - nd2) >= RA; \
        WK = S2 ? (-(nd2 + RA) / den) : 0.f; \
        if (aa && (S || AK != 0.f)) chg = true; \
        if (aa && fabsf(nd2) > THRESH) fireN |= 1u << K; \
        if (WK != 0.f) nzN |= 1u << K; \
        PK = np2; DK = nd2; }
    UPD(p0, d0, a0, 0, w0)
    UPD(p1, d1, a1, 1, w1)
    UPD(p2v, d2v, a2, 2, w2)
    UPD(p3, d3, a3, 3, w3)
#undef UPD

    if (last) {
        if (rok) {
            outp[(4 * sh + 0) * (size_t)N + row] = p0;
            outp[(4 * sh + 1) * (size_t)N + row] = p1;
            outp[(4 * sh + 2) * (size_t)N + row] = p2v;
            outp[(4 * sh + 3) * (size_t)N + row] = p3;
        }
    } else {
        int nzl = (nzN != 0) ? 1 : 0;
        int rn = nzl | __shfl_xor(nzl, 1);          // row has any nonzero dpw
        if (rok && chg) {
            float4* pp = (float4*)(pd + (size_t)row * NS + 4 * sh);
            pp[0] = make_float4(p0, d0, p1, d1);
            pp[1] = make_float4(p2v, d2v, p3, d3);
        }
        if (rok && rn) {
            *(float4*)(dout + (size_t)row * NS + 4 * sh) = make_float4(w0, w1, w2, w3);
        }
        int rnv = __shfl(rn, (lane & 31) * 2);      // lane i <- row i's rn
        unsigned long long bw = __ballot(lane < 32 && rnv);
        if (lane == 0 && wid < NW) maskOut[wid] = (unsigned)bw;

        int wm = 0;
#pragma unroll
        for (int b = 0; b < 4; ++b) {
            unsigned long long bb = __ballot((fireN >> b) & 1);
            if (bb & 0x5555555555555555ull) wm |= 1 << b;        // sh=0: seeds 0..3
            if (bb & 0xAAAAAAAAAAAAAAAAull) wm |= 1 << (4 + b);  // sh=1: seeds 4..7
        }
        if (wm && lane == 0) {
            int hsh = wid & (NMIR - 1);
            int cur = __hip_atomic_load(&flagOut[hsh], __ATOMIC_RELAXED,
                                        __HIP_MEMORY_SCOPE_AGENT);
            if ((cur & wm) != wm) atomicOr(&flagOut[hsh], wm);
        }
    }
}

extern "C" void kernel_launch(void* const* d_in, const int* in_sizes, int n_in,
                              void* d_out, int out_size, void* d_ws, size_t ws_size,
                              hipStream_t stream) {
    const int*   adj_row = (const int*)  d_in[0];
    const int*   adj_col = (const int*)  d_in[1];
    const float* deg     = (const float*)d_in[3];
    const int*   seeds   = (const int*)  d_in[4];
    const int E = in_sizes[0];
    const int N = in_sizes[3];
    float* out = (float*)d_out;

    // workspace carve-up (256B aligned). dpwA aliases d_out:
    // din at k=19 is dpwB (19 swaps), so writing out over dpwA is safe.
    char* base = (char*)d_ws;
    size_t off = 0;
    auto carve = [&](size_t bytes) -> void* {
        off = (off + 255) & ~(size_t)255;
        void* ptr = base + off;
        off += bytes;
        return ptr;
    };
    float2*   pd     = (float2*)  carve((size_t)N * NS * 8);
    float*    dpwB   = (float*)   carve((size_t)N * NS * 4);
    int*      cols   = (int*)     carve((size_t)(E + SPAN) * 4);
    int*      offs   = (int*)     carve((size_t)(N + 1) * 4);
    int*      cursor = (int*)     carve((size_t)N * 4);
    int*      bsums  = (int*)     carve((size_t)1024 * 4);
    int*      boffs  = (int*)     carve((size_t)1024 * 4);
    int*      flagM  = (int*)     carve((size_t)(NITER + 1) * NMIR * 4);
    unsigned* maskA  = (unsigned*)carve((size_t)NWMAX * 4);
    unsigned* maskB  = (unsigned*)carve((size_t)NWMAX * 4);
    float*    dpwA   = out;     // aliased

    int nb = (N + 255) / 256;      // 391 blocks
    init_kernel<<<nb, 256, 0, stream>>>(deg, seeds, pd, dpwA, cursor, flagM, maskA, N);
    block_sum_kernel<<<nb, 256, 0, stream>>>(deg, bsums, N);
    scan_sums_kernel<<<1, 1024, 0, stream>>>(bsums, boffs, nb);
    write_offs_kernel<<<nb, 256, 0, stream>>>(deg, boffs, offs, N, E);
    int chunks = (E + ECHUNK - 1) / ECHUNK;
    scatter_kernel<<<chunks * NBIN, 256, 0, stream>>>(adj_row, adj_col, offs, cursor,
                                                      cols, E, N);

    float*    din   = dpwA;
    float*    dout_ = dpwB;
    unsigned* mIn   = maskA;
    unsigned* mOut  = maskB;
    int rowsPerBlk = W4 * CHW;                         // 128
    int ub = (N + rowsPerBlk - 1) / rowsPerBlk;        // 782 blocks
    for (int k = 0; k < NITER; ++k) {
        int last = (k == NITER - 1) ? 1 : 0;
        update_kernel<<<ub, BLK, 0, stream>>>(offs, cols, deg,
                                              flagM + k * NMIR, flagM + (k + 1) * NMIR,
                                              mIn, mOut, din, dout_, pd, out, last, N);
        float* t = din; din = dout_; dout_ = t;
        unsigned* mt = mIn; mIn = mOut; mOut = mt;
    }
}

// Round 11
// 370.673 us; speedup vs baseline: 3.3139x; 1.0235x over previous
//
#include <hip/hip_runtime.h>

#define ALPHA   0.15f
#define RA      (1e-4f * 0.15f)                  // RHO*ALPHA
#define THRESH  ((1.0f + 0.01f) * 1e-4f * 0.15f) // (1+eps)*RHO*ALPHA
#define NITER   20
#define NS      8
#define NMIR    64       // flag mirrors to spread atomicOr contention
#define CHW     16       // rows per wave (4 lanes/row, 2 seeds/lane)
#define BLK     256      // 4 waves/block -> 64 rows/block -> 1563 blocks
#define W4      (BLK / 64)
#define SPAN    384      // LDS cols capacity per wave (mean 256, +8 sigma)
#define NBIN    8        // scatter row-bins (== XCDs)
#define ECHUNK  2048     // edges per scatter chunk
#define NWMAX   3136     // mask words capacity (N/32 = 3125)

// ---------------------------------------------------------------------------
// init: pd=(0,d0); dpw0 = dpk0/(deg+1e-12); cursor=0; flag mirrors; maskA;
// also produces per-block deg sums (absorbed block_sum_kernel).
// ---------------------------------------------------------------------------
__global__ void init_kernel(const float* __restrict__ deg, const int* __restrict__ seeds,
                            float2* __restrict__ pd, float* __restrict__ dpw,
                            int* __restrict__ cursor, int* __restrict__ flagM,
                            unsigned* __restrict__ maskA, int* __restrict__ blockSums,
                            int N) {
    int idx = blockIdx.x * blockDim.x + threadIdx.x;
    int NW = (N + 31) >> 5;

    // per-block deg sum (for the scan)
    int v = (idx < N) ? (int)deg[idx] : 0;
#pragma unroll
    for (int o = 1; o < 64; o <<= 1) v += __shfl_xor(v, o);
    __shared__ int ws[4];
    if ((threadIdx.x & 63) == 0) ws[threadIdx.x >> 6] = v;
    __syncthreads();
    if (threadIdx.x == 0) blockSums[blockIdx.x] = ws[0] + ws[1] + ws[2] + ws[3];

    if (idx < (NITER + 1) * NMIR) {
        int fv = 0;
        if (idx == 0) {
            for (int s = 0; s < NS; ++s) {
                float m = ALPHA / fmaxf(deg[seeds[s]], 1e-12f);
                if (m > THRESH) fv |= (1 << s);
            }
        }
        flagM[idx] = fv;
    }
    if (idx < NW) {                 // frontier mask for iter 0: seed bits
        unsigned mv = 0;
        for (int s = 0; s < NS; ++s) {
            int sd = seeds[s];
            bool S0 = (ALPHA / fmaxf(deg[sd], 1e-12f)) >= RA;
            if (S0 && (sd >> 5) == idx) mv |= (1u << (sd & 31));
        }
        maskA[idx] = mv;
    }
    if (idx >= N) return;
    cursor[idx] = 0;
    float dv[NS];
#pragma unroll
    for (int s = 0; s < NS; ++s) dv[s] = 0.f;
#pragma unroll
    for (int s = 0; s < NS; ++s) {
        if (seeds[s] == idx) dv[s] = -ALPHA / fmaxf(deg[idx], 1e-12f);
    }
    float den = deg[idx] + 1e-12f;
#pragma unroll
    for (int s = 0; s < NS; ++s) {
        pd[idx * NS + s] = make_float2(0.f, dv[s]);
        bool S = (0.f - dv[s]) >= RA;
        dpw[idx * NS + s] = S ? (-(dv[s] + RA) / den) : 0.f;
    }
}

// ---------------------------------------------------------------------------
// scan of per-block sums + per-element offsets (two tiny kernels)
// ---------------------------------------------------------------------------
__global__ void scan_sums_kernel(const int* __restrict__ blockSums, int* __restrict__ blockOffs, int nB) {
    __shared__ int buf[1024];
    int t = threadIdx.x;
    int v = (t < nB) ? blockSums[t] : 0;
    buf[t] = v;
    __syncthreads();
    for (int o = 1; o < 1024; o <<= 1) {
        int u = (t >= o) ? buf[t - o] : 0;
        __syncthreads();
        buf[t] += u;
        __syncthreads();
    }
    if (t < nB) blockOffs[t] = buf[t] - v;  // exclusive
}

__global__ void write_offs_kernel(const float* __restrict__ deg, const int* __restrict__ blockOffs,
                                  int* __restrict__ offs, int N, int E) {
    int t = threadIdx.x;
    int i = blockIdx.x * 256 + t;
    int v = (i < N) ? (int)deg[i] : 0;
    __shared__ int buf[256];
    buf[t] = v;
    __syncthreads();
    for (int o = 1; o < 256; o <<= 1) {
        int u = (t >= o) ? buf[t - o] : 0;
        __syncthreads();
        buf[t] += u;
        __syncthreads();
    }
    int excl = buf[t] - v;
    if (i < N) offs[i] = blockOffs[blockIdx.x] + excl;
    if (i == 0) offs[N] = E;   // sum(deg) == E by construction (deg = bincount(row))
}

// ---------------------------------------------------------------------------
// scatter COO -> CSR, XCD-binned; record = plain col (4B).
// ---------------------------------------------------------------------------
__global__ void scatter_kernel(const int* __restrict__ row, const int* __restrict__ col,
                               const int* __restrict__ offs, int* __restrict__ cursor,
                               int* __restrict__ cols, int E, int N) {
    int bin = blockIdx.x & (NBIN - 1);
    int chunk = blockIdx.x >> 3;
    int binW = (N + NBIN - 1) / NBIN;
    int binLo = bin * binW;
    int binHi = min(N, binLo + binW);
    int e = chunk * ECHUNK + threadIdx.x;
#pragma unroll
    for (int i = 0; i < ECHUNK / 256; ++i, e += 256) {
        if (e < E) {
            int r = row[e];
            if (r >= binLo && r < binHi) {
                int pos = offs[r] + atomicAdd(&cursor[r], 1);
                cols[pos] = col[e];
            }
        }
    }
}

// ---------------------------------------------------------------------------
// one iteration. Wave = 16 rows x 4 lanes/row (lane quarter q owns seeds
// 2q,2q+1). Stage frontier bitmask (block) + wave CSR slice with mask folded
// in (-1 sentinel). Gather: lane walks its row's slots, float2 per edge (the
// 4 lanes of an edge cover the row's 32B din line). No cross-lane reduction.
// Fused scalar update (2 seeds/lane); pd/dout stores skipped when dead.
// ---------------------------------------------------------------------------
__global__ __launch_bounds__(BLK, 6) void update_kernel(
        const int* __restrict__ offs, const int* __restrict__ cols,
        const float* __restrict__ deg,
        const int* __restrict__ flagIn, int* __restrict__ flagOut,
        const unsigned* __restrict__ maskIn, unsigned* __restrict__ maskOut,
        const float* __restrict__ din, float* __restrict__ dout,
        float2* __restrict__ pd, float* __restrict__ outp, int last, int N) {
    __shared__ unsigned smask[NWMAX];
    __shared__ int sColsAll[W4 * SPAN];
    __shared__ unsigned sRow[W4];
    int tid = threadIdx.x;
    int w = tid >> 6;
    int lane = tid & 63;
    int wid = blockIdx.x * W4 + w;
    int base = wid * CHW;
    int NW = (N + 31) >> 5;
    int* sCols = sColsAll + w * SPAN;

    int r4 = lane >> 2;                     // row-in-wave 0..15
    int q  = lane & 3;                      // quarter: seeds 2q, 2q+1
    int row = base + r4;
    bool rok = row < N;

    // iteration-k flags: OR over 64 mirrors via shuffles (grid-uniform value)
    int fm = flagIn[lane];
#pragma unroll
    for (int o = 1; o < 64; o <<= 1) fm |= __shfl_xor(fm, o);

    if (fm == 0) {                          // globally converged: p frozen
        if (last && rok) {
            float4 pv4 = ((const float4*)(pd + (size_t)row * NS))[q];
            outp[(2 * q + 0) * (size_t)N + row] = pv4.x;
            outp[(2 * q + 1) * (size_t)N + row] = pv4.z;
        }
        return;
    }

    for (int i = tid; i < NW; i += BLK) smask[i] = maskIn[i];
    __syncthreads();

    int offv = 0;
    if (lane <= CHW) offv = offs[min(base + lane, N)];
    int off0 = __shfl(offv, 0);
    int span = __shfl(offv, CHW) - off0;
    int e0 = __shfl(offv, r4);
    int e1 = __shfl(offv, r4 + 1);
    int rel = e0 - off0, ndg = e1 - e0;

    bool fits = (span <= SPAN);
    if (fits) {                             // stage cols with mask folded in
        for (int i = lane; i < span; i += 64) {
            int cc = cols[off0 + i];
            sCols[i] = ((smask[cc >> 5] >> (cc & 31)) & 1u) ? cc : -1;
        }
    }
    // no barrier needed: sCols region is wave-private

    int mx = ndg;
#pragma unroll
    for (int o = 1; o < 64; o <<= 1) mx = max(mx, __shfl_xor(mx, o));

    // hoisted row state (issues before/with the gather loop)
    float dg = 1.0f;
    float4 pdv = make_float4(0.f, 0.f, 0.f, 0.f);
    if (rok) {
        dg = deg[row];
        pdv = ((const float4*)(pd + (size_t)row * NS))[q];
    }

    float a0 = 0.f, a1 = 0.f;
    const float2* din2 = (const float2*)din;
    if (fits) {
#pragma unroll 8
        for (int i = 0; i < mx; ++i) {
            int cc = (i < ndg) ? sCols[rel + i] : -1;
            if (cc >= 0) {
                float2 v = din2[(size_t)cc * 4 + q];
                a0 += v.x; a1 += v.y;
            }
        }
    } else {                                // astronomically rare slice
        for (int i = 0; i < mx; ++i) {
            if (i < ndg) {
                int cc = cols[e0 + i];
                if ((smask[cc >> 5] >> (cc & 31)) & 1u) {
                    float2 v = din2[(size_t)cc * 4 + q];
                    a0 += v.x; a1 += v.y;
                }
            }
        }
    }

    float di = 1.0f / fmaxf(dg, 1e-12f);
    float hf = 0.5f * (1.0f - ALPHA) * di;
    float den = dg + 1e-12f;

    float p0 = pdv.x, d0 = pdv.y, p1 = pdv.z, d1 = pdv.w;
    float w0, w1;
    unsigned fireN = 0, nzN = 0;
    bool chg = false;

#define UPD(PK, DK, AK, B, WK) { \
        bool S = (PK - DK) >= RA; \
        float dpkv = S ? -(DK + RA) : 0.f; \
        float dS  = (1.0f - di) * DK - RA * di - hf * dpkv - hf * AK; \
        float dnb = DK - hf * AK; \
        bool aa = (fm >> (2 * q + B)) & 1; \
        float nd2 = aa ? (S ? dS : dnb) : DK; \
        float np2 = aa ? (S ? PK + dpkv : PK) : PK; \
        bool S2 = (np2 - nd2) >= RA; \
        WK = S2 ? (-(nd2 + RA) / den) : 0.f; \
        if (aa && (S || AK != 0.f)) chg = true; \
        if (aa && fabsf(nd2) > THRESH) fireN |= 1u << B; \
        if (WK != 0.f) nzN |= 1u << B; \
        PK = np2; DK = nd2; }
    UPD(p0, d0, a0, 0, w0)
    UPD(p1, d1, a1, 1, w1)
#undef UPD

    if (last) {
        if (rok) {
            outp[(2 * q + 0) * (size_t)N + row] = p0;
            outp[(2 * q + 1) * (size_t)N + row] = p1;
        }
    } else {
        int nzl = (nzN != 0) ? 1 : 0;
        nzl |= __shfl_xor(nzl, 1);
        nzl |= __shfl_xor(nzl, 2);                  // row-any-nonzero (all 4 lanes)
        if (rok && chg) {
            ((float4*)(pd + (size_t)row * NS))[q] = make_float4(p0, d0, p1, d1);
        }
        if (rok && nzl) {
            ((float2*)(dout + (size_t)row * NS))[q] = make_float2(w0, w1);
        }
        // wave mask bits: lane i<16 <- row i's nzl
        int rnv = __shfl(nzl, (lane & 15) * 4);
        unsigned long long bw = __ballot(lane < 16 && rnv);
        if (lane == 0) sRow[w] = (unsigned)(bw & 0xFFFFull);
        __syncthreads();
        if (tid < 2) {
            unsigned wv = sRow[2 * tid] | (sRow[2 * tid + 1] << 16);
            int word = blockIdx.x * 2 + tid;
            if (word < NW) maskOut[word] = wv;
        }

        int wm = 0;
        unsigned long long bb0 = __ballot(fireN & 1);
        unsigned long long bb1 = __ballot((fireN >> 1) & 1);
#pragma unroll
        for (int qq = 0; qq < 4; ++qq) {
            if (bb0 & (0x1111111111111111ull << qq)) wm |= 1 << (2 * qq);
            if (bb1 & (0x1111111111111111ull << qq)) wm |= 1 << (2 * qq + 1);
        }
        if (wm && lane == 0) {
            int hsh = wid & (NMIR - 1);
            int cur = __hip_atomic_load(&flagOut[hsh], __ATOMIC_RELAXED,
                                        __HIP_MEMORY_SCOPE_AGENT);
            if ((cur & wm) != wm) atomicOr(&flagOut[hsh], wm);
        }
    }
}

extern "C" void kernel_launch(void* const* d_in, const int* in_sizes, int n_in,
                              void* d_out, int out_size, void* d_ws, size_t ws_size,
                              hipStream_t stream) {
    const int*   adj_row = (const int*)  d_in[0];
    const int*   adj_col = (const int*)  d_in[1];
    const float* deg     = (const float*)d_in[3];
    const int*   seeds   = (const int*)  d_in[4];
    const int E = in_sizes[0];
    const int N = in_sizes[3];
    float* out = (float*)d_out;

    // workspace carve-up (256B aligned). dpwA aliases d_out:
    // din at k=19 is dpwB (19 swaps), so writing out over dpwA is safe.
    char* base = (char*)d_ws;
    size_t off = 0;
    auto carve = [&](size_t bytes) -> void* {
        off = (off + 255) & ~(size_t)255;
        void* ptr = base + off;
        off += bytes;
        return ptr;
    };
    float2*   pd     = (float2*)  carve((size_t)N * NS * 8);
    float*    dpwB   = (float*)   carve((size_t)N * NS * 4);
    int*      cols   = (int*)     carve((size_t)(E + SPAN) * 4);
    int*      offs   = (int*)     carve((size_t)(N + 1) * 4);
    int*      cursor = (int*)     carve((size_t)N * 4);
    int*      bsums  = (int*)     carve((size_t)1024 * 4);
    int*      boffs  = (int*)     carve((size_t)1024 * 4);
    int*      flagM  = (int*)     carve((size_t)(NITER + 1) * NMIR * 4);
    unsigned* maskA  = (unsigned*)carve((size_t)NWMAX * 4);
    unsigned* maskB  = (unsigned*)carve((size_t)NWMAX * 4);
    float*    dpwA   = out;     // aliased

    int nb = (N + 255) / 256;      // 391 blocks
    init_kernel<<<nb, 256, 0, stream>>>(deg, seeds, pd, dpwA, cursor, flagM, maskA,
                                        bsums, N);
    scan_sums_kernel<<<1, 1024, 0, stream>>>(bsums, boffs, nb);
    write_offs_kernel<<<nb, 256, 0, stream>>>(deg, boffs, offs, N, E);
    int chunks = (E + ECHUNK - 1) / ECHUNK;
    scatter_kernel<<<chunks * NBIN, 256, 0, stream>>>(adj_row, adj_col, offs, cursor,
                                                      cols, E, N);

    float*    din   = dpwA;
    float*    dout_ = dpwB;
    unsigned* mIn   = maskA;
    unsigned* mOut  = maskB;
    int rowsPerBlk = W4 * CHW;                         // 64
    int ub = (N + rowsPerBlk - 1) / rowsPerBlk;        // 1563 blocks
    for (int k = 0; k < NITER; ++k) {
        int last = (k == NITER - 1) ? 1 : 0;
        update_kernel<<<ub, BLK, 0, stream>>>(offs, cols, deg,
                                              flagM + k * NMIR, flagM + (k + 1) * NMIR,
                                              mIn, mOut, din, dout_, pd, out, last, N);
        float* t = din; din = dout_; dout_ = t;
        unsigned* mt = mIn; mIn = mOut; mOut = mt;
    }
}